// Round 1
// baseline (462.693 us; speedup 1.0000x reference)
//
#include <hip/hip_runtime.h>
#include <stdint.h>

typedef __bf16 bf16x8 __attribute__((ext_vector_type(8)));
typedef float f32x4 __attribute__((ext_vector_type(4)));

static constexpr int BB = 4, TT = 2048, CC = 1024, HH = 16, DH = 64;
static constexpr int MM = BB * TT;   // 8192
static constexpr int N1 = 3 * CC;    // 3072
static constexpr int KK = CC;        // 1024

__device__ __forceinline__ unsigned short f2bf(float f) {
  uint32_t u = __builtin_bit_cast(uint32_t, f);
  u += 0x7FFFu + ((u >> 16) & 1u);
  return (unsigned short)(u >> 16);
}

__device__ __forceinline__ void async16(const void* g, void* l) {
  __builtin_amdgcn_global_load_lds((const __attribute__((address_space(1))) void*)g,
                                   (__attribute__((address_space(3))) void*)l, 16, 0, 0);
}

// ---- f32 -> bf16, 8 elems/thread ----
__global__ __launch_bounds__(256) void k_cvt(const float* __restrict__ src,
                                             unsigned short* __restrict__ dst) {
  int i = blockIdx.x * 256 + threadIdx.x;
  const float4* s = (const float4*)src + (size_t)i * 2;
  float4 a = s[0], b = s[1];
  union { unsigned short h[8]; uint4 v; } o;
  o.h[0] = f2bf(a.x); o.h[1] = f2bf(a.y); o.h[2] = f2bf(a.z); o.h[3] = f2bf(a.w);
  o.h[4] = f2bf(b.x); o.h[5] = f2bf(b.y); o.h[6] = f2bf(b.z); o.h[7] = f2bf(b.w);
  ((uint4*)dst)[i] = o.v;
}

// ---- transpose + convert: src[R][C] f32 -> dst[C][R] bf16 ----
__global__ __launch_bounds__(256) void k_tcvt(const float* __restrict__ src,
                                              unsigned short* __restrict__ dst,
                                              int R, int C) {
  __shared__ float tile[32][33];
  int tx = threadIdx.x & 31, ty = threadIdx.x >> 5;
  int c0 = blockIdx.x * 32, r0 = blockIdx.y * 32;
#pragma unroll
  for (int i = 0; i < 4; ++i)
    tile[ty + i * 8][tx] = src[(size_t)(r0 + ty + i * 8) * C + c0 + tx];
  __syncthreads();
#pragma unroll
  for (int i = 0; i < 4; ++i)
    dst[(size_t)(c0 + ty + i * 8) * R + r0 + tx] = f2bf(tile[tx][ty + i * 8]);
}

// ---- GEMM C[M][N] = A[M][K] @ Bt[N][K]^T, m97-style 128x128 tile, BK=64 ----
// MODE 0: QKV epilogue (scatter Q*0.125, K, V^T as bf16). MODE 1: f32 out + bias.
template <int MODE>
__global__ __launch_bounds__(256) void k_gemm(
    const unsigned short* __restrict__ A, const unsigned short* __restrict__ Bt,
    const float* __restrict__ bias, int M, int N, int K,
    unsigned short* __restrict__ qo, unsigned short* __restrict__ ko,
    unsigned short* __restrict__ vo, float* __restrict__ fo) {
  __shared__ __attribute__((aligned(16))) unsigned short As[128 * 64];
  __shared__ __attribute__((aligned(16))) unsigned short Bs[128 * 64];
  const int tid = threadIdx.x;
  const int lane = tid & 63;
  const int w = tid >> 6, wr = w >> 1, wc = w & 1;
  const int l15 = lane & 15, l16 = lane >> 4;
  const int m0 = blockIdx.y * 128, n0 = blockIdx.x * 128;

  f32x4 acc[4][4] = {};

  const unsigned short* aSrc = A + (size_t)(m0 + (tid >> 3)) * K + (tid & 7) * 8;
  const unsigned short* bSrc = Bt + (size_t)(n0 + (tid >> 3)) * K + (tid & 7) * 8;
  unsigned short* aDst = &As[tid * 8];
  unsigned short* bDst = &Bs[tid * 8];

#pragma unroll 1
  for (int k0 = 0; k0 < K; k0 += 64) {
#pragma unroll
    for (int i = 0; i < 4; ++i) {
      async16(aSrc + (size_t)i * 32 * K + k0, aDst + i * 2048);
      async16(bSrc + (size_t)i * 32 * K + k0, bDst + i * 2048);
    }
    __syncthreads();
#pragma unroll
    for (int ks = 0; ks < 2; ++ks) {
      bf16x8 af[4], bfr[4];
#pragma unroll
      for (int i = 0; i < 4; ++i)
        af[i] = *(const bf16x8*)&As[(wr * 64 + i * 16 + l15) * 64 + ks * 32 + l16 * 8];
#pragma unroll
      for (int j = 0; j < 4; ++j)
        bfr[j] = *(const bf16x8*)&Bs[(wc * 64 + j * 16 + l15) * 64 + ks * 32 + l16 * 8];
#pragma unroll
      for (int i = 0; i < 4; ++i)
#pragma unroll
        for (int j = 0; j < 4; ++j)
          acc[i][j] = __builtin_amdgcn_mfma_f32_16x16x32_bf16(af[i], bfr[j], acc[i][j], 0, 0, 0);
    }
    __syncthreads();
  }

#pragma unroll
  for (int i = 0; i < 4; ++i) {
#pragma unroll
    for (int j = 0; j < 4; ++j) {
      const int gn = n0 + wc * 64 + j * 16 + l15;
      const float bj = bias[gn];
#pragma unroll
      for (int r = 0; r < 4; ++r) {
        const int gm = m0 + wr * 64 + i * 16 + l16 * 4 + r;
        const float v = acc[i][j][r] + bj;
        if (MODE == 0) {
          const int sel = gn >> 10, rem = gn & 1023;
          const int h = rem >> 6, d = rem & 63;
          const int bb = gm >> 11, t = gm & 2047;
          if (sel == 0)
            qo[((size_t)(bb * HH + h) * TT + t) * DH + d] = f2bf(v * 0.125f);
          else if (sel == 1)
            ko[((size_t)(bb * HH + h) * TT + t) * DH + d] = f2bf(v);
          else
            vo[((size_t)(bb * HH + h) * DH + d) * TT + t] = f2bf(v);
        } else {
          fo[(size_t)gm * N + gn] = v;
        }
      }
    }
  }
}

// ---- flash attention: 64-row Q tile, 4 waves x 16 rows, KV tiles of 128 ----
__global__ __launch_bounds__(256) void k_attn(
    const unsigned short* __restrict__ Q,   // [64][T][64] bh-major, pre-scaled
    const unsigned short* __restrict__ Kx,  // [64][T][64]
    const unsigned short* __restrict__ Vt,  // [64][64][T]  (d-major)
    unsigned short* __restrict__ At) {      // [B][T][C]
  __shared__ __attribute__((aligned(16))) unsigned short Ks[128 * 64];
  __shared__ __attribute__((aligned(16))) unsigned short Vs[64 * 128];
  __shared__ __attribute__((aligned(16))) unsigned short Ps[64 * 128];
  const int tid = threadIdx.x, lane = tid & 63, w = tid >> 6;
  const int l15 = lane & 15, l16 = lane >> 4;
  const int bh = blockIdx.y;
  const int q0 = blockIdx.x * 64;
  const unsigned short* Qp = Q + (size_t)bh * TT * DH;
  const unsigned short* Kp = Kx + (size_t)bh * TT * DH;
  const unsigned short* Vp = Vt + (size_t)bh * DH * TT;

  bf16x8 qf[2];
  {
    const int qrow = q0 + w * 16 + l15;
    qf[0] = *(const bf16x8*)&Qp[(size_t)qrow * DH + l16 * 8];
    qf[1] = *(const bf16x8*)&Qp[(size_t)qrow * DH + 32 + l16 * 8];
  }

  float m_run[4], l_run[4];
  f32x4 o[4] = {};
#pragma unroll
  for (int r = 0; r < 4; ++r) { m_run[r] = -1e30f; l_run[r] = 0.f; }

#pragma unroll 1
  for (int kt = 0; kt < TT / 128; ++kt) {
    const int kv0 = kt * 128;
    __syncthreads();  // previous tile's LDS reads done before overwrite
#pragma unroll
    for (int i = 0; i < 4; ++i) {
      async16(Kp + (size_t)(kv0 + i * 32 + (tid >> 3)) * DH + (tid & 7) * 8,
              &Ks[i * 2048 + tid * 8]);
      async16(Vp + (size_t)(i * 16 + (tid >> 4)) * TT + kv0 + (tid & 15) * 8,
              &Vs[i * 2048 + tid * 8]);
    }
    __syncthreads();

    // S = Q K^T  (16 q-rows x 128 kv)
    f32x4 s[8] = {};
#pragma unroll
    for (int ks = 0; ks < 2; ++ks)
#pragma unroll
      for (int j = 0; j < 8; ++j) {
        bf16x8 kf = *(const bf16x8*)&Ks[(j * 16 + l15) * 64 + ks * 32 + l16 * 8];
        s[j] = __builtin_amdgcn_mfma_f32_16x16x32_bf16(qf[ks], kf, s[j], 0, 0, 0);
      }

    // online softmax (rows are 16-lane groups; reduce via shfl_xor 1,2,4,8)
    float p[8][4];
#pragma unroll
    for (int r = 0; r < 4; ++r) {
      float mt = s[0][r];
#pragma unroll
      for (int j = 1; j < 8; ++j) mt = fmaxf(mt, s[j][r]);
      mt = fmaxf(mt, __shfl_xor(mt, 1));
      mt = fmaxf(mt, __shfl_xor(mt, 2));
      mt = fmaxf(mt, __shfl_xor(mt, 4));
      mt = fmaxf(mt, __shfl_xor(mt, 8));
      const float mnew = fmaxf(m_run[r], mt);
      const float sc = exp2f((m_run[r] - mnew) * 1.44269504088896f);
      float rs = 0.f;
#pragma unroll
      for (int j = 0; j < 8; ++j) {
        p[j][r] = exp2f((s[j][r] - mnew) * 1.44269504088896f);
        rs += p[j][r];
      }
      rs += __shfl_xor(rs, 1);
      rs += __shfl_xor(rs, 2);
      rs += __shfl_xor(rs, 4);
      rs += __shfl_xor(rs, 8);
      l_run[r] = l_run[r] * sc + rs;
      m_run[r] = mnew;
#pragma unroll
      for (int n = 0; n < 4; ++n) o[n][r] *= sc;
    }

    // P -> LDS (wave-private 16 rows), then PV
#pragma unroll
    for (int j = 0; j < 8; ++j)
#pragma unroll
      for (int r = 0; r < 4; ++r)
        Ps[(w * 16 + l16 * 4 + r) * 128 + j * 16 + l15] = f2bf(p[j][r]);

#pragma unroll
    for (int kk = 0; kk < 4; ++kk) {
      bf16x8 ap = *(const bf16x8*)&Ps[(w * 16 + l15) * 128 + kk * 32 + l16 * 8];
#pragma unroll
      for (int n = 0; n < 4; ++n) {
        bf16x8 bv = *(const bf16x8*)&Vs[(n * 16 + l15) * 128 + kk * 32 + l16 * 8];
        o[n] = __builtin_amdgcn_mfma_f32_16x16x32_bf16(ap, bv, o[n], 0, 0, 0);
      }
    }
  }

#pragma unroll
  for (int n = 0; n < 4; ++n)
#pragma unroll
    for (int r = 0; r < 4; ++r) {
      const int t = q0 + w * 16 + l16 * 4 + r;
      const int d = n * 16 + l15;
      const int bb = bh >> 4, h = bh & 15;
      At[((size_t)bb * TT + t) * CC + h * DH + d] = f2bf(o[n][r] / l_run[r]);
    }
}

extern "C" void kernel_launch(void* const* d_in, const int* in_sizes, int n_in,
                              void* d_out, int out_size, void* d_ws, size_t ws_size,
                              hipStream_t stream) {
  const float* x = (const float*)d_in[0];
  const float* Wqkv = (const float*)d_in[1];
  const float* bqkv = (const float*)d_in[2];
  const float* Wout = (const float*)d_in[3];
  const float* bout = (const float*)d_in[4];
  float* out = (float*)d_out;

  char* ws = (char*)d_ws;
  unsigned short* Xb  = (unsigned short*)(ws);                      // 16 MB
  unsigned short* WqT = (unsigned short*)(ws + (16ull << 20));      // 6 MB
  unsigned short* WoT = (unsigned short*)(ws + (22ull << 20));      // 2 MB
  unsigned short* Qb  = (unsigned short*)(ws + (24ull << 20));      // 16 MB
  unsigned short* Kb  = (unsigned short*)(ws + (40ull << 20));      // 16 MB
  unsigned short* Vt  = (unsigned short*)(ws + (56ull << 20));      // 16 MB
  unsigned short* At  = (unsigned short*)(ws + (72ull << 20));      // 16 MB (88 total)

  k_cvt<<<dim3((MM * KK) / (256 * 8)), 256, 0, stream>>>(x, Xb);
  k_tcvt<<<dim3(N1 / 32, KK / 32), 256, 0, stream>>>(Wqkv, WqT, KK, N1);
  k_tcvt<<<dim3(CC / 32, KK / 32), 256, 0, stream>>>(Wout, WoT, KK, CC);
  k_gemm<0><<<dim3(N1 / 128, MM / 128), 256, 0, stream>>>(
      Xb, WqT, bqkv, MM, N1, KK, Qb, Kb, Vt, nullptr);
  k_attn<<<dim3(TT / 64, BB * HH), 256, 0, stream>>>(Qb, Kb, Vt, At);
  k_gemm<1><<<dim3(CC / 128, MM / 128), 256, 0, stream>>>(
      At, WoT, bout, MM, CC, KK, nullptr, nullptr, nullptr, out);
}

// Round 2
// 352.870 us; speedup vs baseline: 1.3112x; 1.3112x over previous
//
#include <hip/hip_runtime.h>
#include <stdint.h>

typedef __bf16 bf16x8 __attribute__((ext_vector_type(8)));
typedef float f32x4 __attribute__((ext_vector_type(4)));

static constexpr int BB = 4, TT = 2048, CC = 1024, HH = 16, DH = 64;
static constexpr int MM = BB * TT;   // 8192
static constexpr int N1 = 3 * CC;    // 3072
static constexpr int KK = CC;        // 1024

__device__ __forceinline__ unsigned short f2bf(float f) {
  uint32_t u = __builtin_bit_cast(uint32_t, f);
  u += 0x7FFFu + ((u >> 16) & 1u);
  return (unsigned short)(u >> 16);
}

__device__ __forceinline__ void async16(const void* g, void* l) {
  __builtin_amdgcn_global_load_lds((const __attribute__((address_space(1))) void*)g,
                                   (__attribute__((address_space(3))) void*)l, 16, 0, 0);
}

// ---- f32 -> bf16, 8 elems/thread ----
__global__ __launch_bounds__(256) void k_cvt(const float* __restrict__ src,
                                             unsigned short* __restrict__ dst) {
  int i = blockIdx.x * 256 + threadIdx.x;
  const float4* s = (const float4*)src + (size_t)i * 2;
  float4 a = s[0], b = s[1];
  union { unsigned short h[8]; uint4 v; } o;
  o.h[0] = f2bf(a.x); o.h[1] = f2bf(a.y); o.h[2] = f2bf(a.z); o.h[3] = f2bf(a.w);
  o.h[4] = f2bf(b.x); o.h[5] = f2bf(b.y); o.h[6] = f2bf(b.z); o.h[7] = f2bf(b.w);
  ((uint4*)dst)[i] = o.v;
}

// ---- transpose + convert: src[R][C] f32 -> dst[C][R] bf16 ----
__global__ __launch_bounds__(256) void k_tcvt(const float* __restrict__ src,
                                              unsigned short* __restrict__ dst,
                                              int R, int C) {
  __shared__ float tile[32][33];
  int tx = threadIdx.x & 31, ty = threadIdx.x >> 5;
  int c0 = blockIdx.x * 32, r0 = blockIdx.y * 32;
#pragma unroll
  for (int i = 0; i < 4; ++i)
    tile[ty + i * 8][tx] = src[(size_t)(r0 + ty + i * 8) * C + c0 + tx];
  __syncthreads();
#pragma unroll
  for (int i = 0; i < 4; ++i)
    dst[(size_t)(c0 + ty + i * 8) * R + r0 + tx] = f2bf(tile[tx][ty + i * 8]);
}

// ---- GEMM C[M][N] = A[M][K] @ Bt[N][K]^T, m97-style 128x128 tile, BK=64 ----
// MODE 0: QKV epilogue (scatter Q*0.125, K, V^T as bf16). MODE 1: f32 out + bias.
template <int MODE>
__global__ __launch_bounds__(256) void k_gemm(
    const unsigned short* __restrict__ A, const unsigned short* __restrict__ Bt,
    const float* __restrict__ bias, int M, int N, int K,
    unsigned short* __restrict__ qo, unsigned short* __restrict__ ko,
    unsigned short* __restrict__ vo, float* __restrict__ fo) {
  __shared__ __attribute__((aligned(16))) unsigned short As[128 * 64];
  __shared__ __attribute__((aligned(16))) unsigned short Bs[128 * 64];
  const int tid = threadIdx.x;
  const int lane = tid & 63;
  const int w = tid >> 6, wr = w >> 1, wc = w & 1;
  const int l15 = lane & 15, l16 = lane >> 4;
  const int m0 = blockIdx.y * 128, n0 = blockIdx.x * 128;

  f32x4 acc[4][4] = {};

  const unsigned short* aSrc = A + (size_t)(m0 + (tid >> 3)) * K + (tid & 7) * 8;
  const unsigned short* bSrc = Bt + (size_t)(n0 + (tid >> 3)) * K + (tid & 7) * 8;
  unsigned short* aDst = &As[tid * 8];
  unsigned short* bDst = &Bs[tid * 8];

#pragma unroll 1
  for (int k0 = 0; k0 < K; k0 += 64) {
#pragma unroll
    for (int i = 0; i < 4; ++i) {
      async16(aSrc + (size_t)i * 32 * K + k0, aDst + i * 2048);
      async16(bSrc + (size_t)i * 32 * K + k0, bDst + i * 2048);
    }
    __syncthreads();
#pragma unroll
    for (int ks = 0; ks < 2; ++ks) {
      bf16x8 af[4], bfr[4];
#pragma unroll
      for (int i = 0; i < 4; ++i)
        af[i] = *(const bf16x8*)&As[(wr * 64 + i * 16 + l15) * 64 + ks * 32 + l16 * 8];
#pragma unroll
      for (int j = 0; j < 4; ++j)
        bfr[j] = *(const bf16x8*)&Bs[(wc * 64 + j * 16 + l15) * 64 + ks * 32 + l16 * 8];
#pragma unroll
      for (int i = 0; i < 4; ++i)
#pragma unroll
        for (int j = 0; j < 4; ++j)
          acc[i][j] = __builtin_amdgcn_mfma_f32_16x16x32_bf16(af[i], bfr[j], acc[i][j], 0, 0, 0);
    }
    __syncthreads();
  }

#pragma unroll
  for (int i = 0; i < 4; ++i) {
#pragma unroll
    for (int j = 0; j < 4; ++j) {
      const int gn = n0 + wc * 64 + j * 16 + l15;
      const float bj = bias[gn];
#pragma unroll
      for (int r = 0; r < 4; ++r) {
        const int gm = m0 + wr * 64 + i * 16 + l16 * 4 + r;
        const float v = acc[i][j][r] + bj;
        if (MODE == 0) {
          const int sel = gn >> 10, rem = gn & 1023;
          const int h = rem >> 6, d = rem & 63;
          const int bb = gm >> 11, t = gm & 2047;
          if (sel == 0)
            qo[((size_t)(bb * HH + h) * TT + t) * DH + d] = f2bf(v * 0.125f);
          else if (sel == 1)
            ko[((size_t)(bb * HH + h) * TT + t) * DH + d] = f2bf(v);
          else
            vo[((size_t)(bb * HH + h) * DH + d) * TT + t] = f2bf(v);
        } else {
          fo[(size_t)gm * N + gn] = v;
        }
      }
    }
  }
}

// ---- flash attention: 64-row Q tile, 4 waves x 16 rows, KV tiles of 128 ----
// T2 XOR-swizzle on all three LDS tiles: element-in-row e = c ^ ((row&7)<<3).
// Ks/Vs: linear global_load_lds dest + pre-swizzled GLOBAL source (rule #21).
__global__ __launch_bounds__(256) void k_attn(
    const unsigned short* __restrict__ Q,   // [64][T][64] bh-major, pre-scaled
    const unsigned short* __restrict__ Kx,  // [64][T][64]
    const unsigned short* __restrict__ Vt,  // [64][64][T]  (d-major)
    unsigned short* __restrict__ At) {      // [B][T][C]
  __shared__ __attribute__((aligned(16))) unsigned short Ks[128 * 64];
  __shared__ __attribute__((aligned(16))) unsigned short Vs[64 * 128];
  __shared__ __attribute__((aligned(16))) unsigned short Ps[64 * 128];
  const int tid = threadIdx.x, lane = tid & 63, w = tid >> 6;
  const int l15 = lane & 15, l16 = lane >> 4;
  const int bh = blockIdx.y;
  const int q0 = blockIdx.x * 64;
  const unsigned short* Qp = Q + (size_t)bh * TT * DH;
  const unsigned short* Kp = Kx + (size_t)bh * TT * DH;
  const unsigned short* Vp = Vt + (size_t)bh * DH * TT;

  bf16x8 qf[2];
  {
    const int qrow = q0 + w * 16 + l15;
    qf[0] = *(const bf16x8*)&Qp[(size_t)qrow * DH + l16 * 8];
    qf[1] = *(const bf16x8*)&Qp[(size_t)qrow * DH + 32 + l16 * 8];
  }

  // pre-swizzled staging source offsets (within-row 16B-granule permute)
  const int krow = tid >> 3;                       // K: 8 granules/row (64 elems)
  const int kcol = ((tid & 7) ^ (krow & 7)) * 8;   // swizzled source column
  const int vrow = tid >> 4;                       // V: 16 granules/row (128 elems)
  const int vcol = ((tid & 15) ^ (vrow & 7)) * 8;

  float m_run[4], l_run[4];
  f32x4 o[4] = {};
#pragma unroll
  for (int r = 0; r < 4; ++r) { m_run[r] = -1e30f; l_run[r] = 0.f; }

#pragma unroll 1
  for (int kt = 0; kt < TT / 128; ++kt) {
    const int kv0 = kt * 128;
    __syncthreads();  // previous tile's LDS reads done before overwrite
#pragma unroll
    for (int i = 0; i < 4; ++i) {
      async16(Kp + (size_t)(kv0 + i * 32 + krow) * DH + kcol, &Ks[i * 2048 + tid * 8]);
      async16(Vp + (size_t)(i * 16 + vrow) * TT + kv0 + vcol, &Vs[i * 2048 + tid * 8]);
    }
    __syncthreads();

    // S = Q K^T  (16 q-rows x 128 kv); swizzled Ks read
    f32x4 s[8] = {};
#pragma unroll
    for (int ks = 0; ks < 2; ++ks)
#pragma unroll
      for (int j = 0; j < 8; ++j) {
        bf16x8 kf = *(const bf16x8*)&Ks[(j * 16 + l15) * 64 +
                                        (((ks * 4 + l16) ^ (l15 & 7)) * 8)];
        s[j] = __builtin_amdgcn_mfma_f32_16x16x32_bf16(qf[ks], kf, s[j], 0, 0, 0);
      }

    // online softmax (rows are 16-lane groups; reduce via shfl_xor 1,2,4,8)
    float p[8][4];
#pragma unroll
    for (int r = 0; r < 4; ++r) {
      float mt = s[0][r];
#pragma unroll
      for (int j = 1; j < 8; ++j) mt = fmaxf(mt, s[j][r]);
      mt = fmaxf(mt, __shfl_xor(mt, 1));
      mt = fmaxf(mt, __shfl_xor(mt, 2));
      mt = fmaxf(mt, __shfl_xor(mt, 4));
      mt = fmaxf(mt, __shfl_xor(mt, 8));
      const float mnew = fmaxf(m_run[r], mt);
      const float sc = exp2f((m_run[r] - mnew) * 1.44269504088896f);
      float rs = 0.f;
#pragma unroll
      for (int j = 0; j < 8; ++j) {
        p[j][r] = exp2f((s[j][r] - mnew) * 1.44269504088896f);
        rs += p[j][r];
      }
      rs += __shfl_xor(rs, 1);
      rs += __shfl_xor(rs, 2);
      rs += __shfl_xor(rs, 4);
      rs += __shfl_xor(rs, 8);
      l_run[r] = l_run[r] * sc + rs;
      m_run[r] = mnew;
#pragma unroll
      for (int n = 0; n < 4; ++n) o[n][r] *= sc;
    }

    // P -> LDS (wave-private 16 rows, swizzled), then PV
#pragma unroll
    for (int j = 0; j < 8; ++j)
#pragma unroll
      for (int r = 0; r < 4; ++r) {
        const int prow = w * 16 + l16 * 4 + r;
        Ps[prow * 128 + ((j * 16 + l15) ^ ((prow & 7) << 3))] = f2bf(p[j][r]);
      }

#pragma unroll
    for (int kk = 0; kk < 4; ++kk) {
      bf16x8 ap = *(const bf16x8*)&Ps[(w * 16 + l15) * 128 +
                                      (((kk * 4 + l16) ^ (l15 & 7)) * 8)];
#pragma unroll
      for (int n = 0; n < 4; ++n) {
        bf16x8 bv = *(const bf16x8*)&Vs[(n * 16 + l15) * 128 +
                                        (((kk * 4 + l16) ^ (l15 & 7)) * 8)];
        o[n] = __builtin_amdgcn_mfma_f32_16x16x32_bf16(ap, bv, o[n], 0, 0, 0);
      }
    }
  }

#pragma unroll
  for (int n = 0; n < 4; ++n)
#pragma unroll
    for (int r = 0; r < 4; ++r) {
      const int t = q0 + w * 16 + l16 * 4 + r;
      const int d = n * 16 + l15;
      const int bb = bh >> 4, h = bh & 15;
      At[((size_t)bb * TT + t) * CC + h * DH + d] = f2bf(o[n][r] / l_run[r]);
    }
}

extern "C" void kernel_launch(void* const* d_in, const int* in_sizes, int n_in,
                              void* d_out, int out_size, void* d_ws, size_t ws_size,
                              hipStream_t stream) {
  const float* x = (const float*)d_in[0];
  const float* Wqkv = (const float*)d_in[1];
  const float* bqkv = (const float*)d_in[2];
  const float* Wout = (const float*)d_in[3];
  const float* bout = (const float*)d_in[4];
  float* out = (float*)d_out;

  char* ws = (char*)d_ws;
  unsigned short* Xb  = (unsigned short*)(ws);                      // 16 MB
  unsigned short* WqT = (unsigned short*)(ws + (16ull << 20));      // 6 MB
  unsigned short* WoT = (unsigned short*)(ws + (22ull << 20));      // 2 MB
  unsigned short* Qb  = (unsigned short*)(ws + (24ull << 20));      // 16 MB
  unsigned short* Kb  = (unsigned short*)(ws + (40ull << 20));      // 16 MB
  unsigned short* Vt  = (unsigned short*)(ws + (56ull << 20));      // 16 MB
  unsigned short* At  = (unsigned short*)(ws + (72ull << 20));      // 16 MB (88 total)

  k_cvt<<<dim3((MM * KK) / (256 * 8)), 256, 0, stream>>>(x, Xb);
  k_tcvt<<<dim3(N1 / 32, KK / 32), 256, 0, stream>>>(Wqkv, WqT, KK, N1);
  k_tcvt<<<dim3(CC / 32, KK / 32), 256, 0, stream>>>(Wout, WoT, KK, CC);
  k_gemm<0><<<dim3(N1 / 128, MM / 128), 256, 0, stream>>>(
      Xb, WqT, bqkv, MM, N1, KK, Qb, Kb, Vt, nullptr);
  k_attn<<<dim3(TT / 64, BB * HH), 256, 0, stream>>>(Qb, Kb, Vt, At);
  k_gemm<1><<<dim3(CC / 128, MM / 128), 256, 0, stream>>>(
      At, WoT, bout, MM, CC, KK, nullptr, nullptr, nullptr, out);
}

// Round 3
// 300.556 us; speedup vs baseline: 1.5395x; 1.1741x over previous
//
#include <hip/hip_runtime.h>
#include <stdint.h>

typedef __bf16 bf16x8 __attribute__((ext_vector_type(8)));
typedef float f32x4 __attribute__((ext_vector_type(4)));
typedef float f32x16 __attribute__((ext_vector_type(16)));

static constexpr int BB = 4, TT = 2048, CC = 1024, HH = 16, DH = 64;
static constexpr int MM = BB * TT;   // 8192
static constexpr int N1 = 3 * CC;    // 3072
static constexpr int KK = CC;        // 1024

__device__ __forceinline__ unsigned short f2bf(float f) {
  uint32_t u = __builtin_bit_cast(uint32_t, f);
  u += 0x7FFFu + ((u >> 16) & 1u);
  return (unsigned short)(u >> 16);
}

__device__ __forceinline__ void async16(const void* g, void* l) {
  __builtin_amdgcn_global_load_lds((const __attribute__((address_space(1))) void*)g,
                                   (__attribute__((address_space(3))) void*)l, 16, 0, 0);
}

// ---- f32 -> bf16, 8 elems/thread ----
__global__ __launch_bounds__(256) void k_cvt(const float* __restrict__ src,
                                             unsigned short* __restrict__ dst) {
  int i = blockIdx.x * 256 + threadIdx.x;
  const float4* s = (const float4*)src + (size_t)i * 2;
  float4 a = s[0], b = s[1];
  union { unsigned short h[8]; uint4 v; } o;
  o.h[0] = f2bf(a.x); o.h[1] = f2bf(a.y); o.h[2] = f2bf(a.z); o.h[3] = f2bf(a.w);
  o.h[4] = f2bf(b.x); o.h[5] = f2bf(b.y); o.h[6] = f2bf(b.z); o.h[7] = f2bf(b.w);
  ((uint4*)dst)[i] = o.v;
}

// ---- transpose + convert: src[R][C] f32 -> dst[C][R] bf16 ----
__global__ __launch_bounds__(256) void k_tcvt(const float* __restrict__ src,
                                              unsigned short* __restrict__ dst,
                                              int R, int C) {
  __shared__ float tile[32][33];
  int tx = threadIdx.x & 31, ty = threadIdx.x >> 5;
  int c0 = blockIdx.x * 32, r0 = blockIdx.y * 32;
#pragma unroll
  for (int i = 0; i < 4; ++i)
    tile[ty + i * 8][tx] = src[(size_t)(r0 + ty + i * 8) * C + c0 + tx];
  __syncthreads();
#pragma unroll
  for (int i = 0; i < 4; ++i)
    dst[(size_t)(c0 + ty + i * 8) * R + r0 + tx] = f2bf(tile[tx][ty + i * 8]);
}

// ---- GEMM C[M][N] = A[M][K] @ Bt[N][K]^T, m97-style 128x128 tile, BK=64 ----
// MODE 0: QKV epilogue (scatter Q*0.125*log2e, K, V^T as bf16). MODE 1: f32 out + bias.
template <int MODE>
__global__ __launch_bounds__(256) void k_gemm(
    const unsigned short* __restrict__ A, const unsigned short* __restrict__ Bt,
    const float* __restrict__ bias, int M, int N, int K,
    unsigned short* __restrict__ qo, unsigned short* __restrict__ ko,
    unsigned short* __restrict__ vo, float* __restrict__ fo) {
  __shared__ __attribute__((aligned(16))) unsigned short As[128 * 64];
  __shared__ __attribute__((aligned(16))) unsigned short Bs[128 * 64];
  const int tid = threadIdx.x;
  const int lane = tid & 63;
  const int w = tid >> 6, wr = w >> 1, wc = w & 1;
  const int l15 = lane & 15, l16 = lane >> 4;
  const int m0 = blockIdx.y * 128, n0 = blockIdx.x * 128;

  f32x4 acc[4][4] = {};

  const unsigned short* aSrc = A + (size_t)(m0 + (tid >> 3)) * K + (tid & 7) * 8;
  const unsigned short* bSrc = Bt + (size_t)(n0 + (tid >> 3)) * K + (tid & 7) * 8;
  unsigned short* aDst = &As[tid * 8];
  unsigned short* bDst = &Bs[tid * 8];

#pragma unroll 1
  for (int k0 = 0; k0 < K; k0 += 64) {
#pragma unroll
    for (int i = 0; i < 4; ++i) {
      async16(aSrc + (size_t)i * 32 * K + k0, aDst + i * 2048);
      async16(bSrc + (size_t)i * 32 * K + k0, bDst + i * 2048);
    }
    __syncthreads();
#pragma unroll
    for (int ks = 0; ks < 2; ++ks) {
      bf16x8 af[4], bfr[4];
#pragma unroll
      for (int i = 0; i < 4; ++i)
        af[i] = *(const bf16x8*)&As[(wr * 64 + i * 16 + l15) * 64 + ks * 32 + l16 * 8];
#pragma unroll
      for (int j = 0; j < 4; ++j)
        bfr[j] = *(const bf16x8*)&Bs[(wc * 64 + j * 16 + l15) * 64 + ks * 32 + l16 * 8];
#pragma unroll
      for (int i = 0; i < 4; ++i)
#pragma unroll
        for (int j = 0; j < 4; ++j)
          acc[i][j] = __builtin_amdgcn_mfma_f32_16x16x32_bf16(af[i], bfr[j], acc[i][j], 0, 0, 0);
    }
    __syncthreads();
  }

#pragma unroll
  for (int i = 0; i < 4; ++i) {
#pragma unroll
    for (int j = 0; j < 4; ++j) {
      const int gn = n0 + wc * 64 + j * 16 + l15;
      const float bj = bias[gn];
#pragma unroll
      for (int r = 0; r < 4; ++r) {
        const int gm = m0 + wr * 64 + i * 16 + l16 * 4 + r;
        const float v = acc[i][j][r] + bj;
        if (MODE == 0) {
          const int sel = gn >> 10, rem = gn & 1023;
          const int h = rem >> 6, d = rem & 63;
          const int bb = gm >> 11, t = gm & 2047;
          if (sel == 0)
            qo[((size_t)(bb * HH + h) * TT + t) * DH + d] = f2bf(v * 0.180336892f);
          else if (sel == 1)
            ko[((size_t)(bb * HH + h) * TT + t) * DH + d] = f2bf(v);
          else
            vo[((size_t)(bb * HH + h) * DH + d) * TT + t] = f2bf(v);
        } else {
          fo[(size_t)gm * N + gn] = v;
        }
      }
    }
  }
}

// ---- flash attention, swapped-QK^T 32x32 structure ----
// 4 waves x QBLK=32 q-rows; KVBLK=64, double-buffered LDS K/V (swizzled);
// S^T = mfma(Kfrag, Qfrag): lane holds 32 P-values of ONE q-row (q = lane&31);
// softmax fully in-register (1 shfl_xor(32) per reduce); P -> bf16 in-register,
// half-exchange via 8 shfl_xor(32), feeds PV B-operand directly. O^T -> LDS
// bounce -> coalesced store.
__global__ __launch_bounds__(256) void k_attn(
    const unsigned short* __restrict__ Q,   // [64][T][64] bh-major, scale=0.125*log2e
    const unsigned short* __restrict__ Kx,  // [64][T][64]
    const unsigned short* __restrict__ Vt,  // [64][64][T]  (d-major)
    unsigned short* __restrict__ At) {      // [B][T][C]
  __shared__ __attribute__((aligned(16))) unsigned short Ks[2][64 * 64];
  __shared__ __attribute__((aligned(16))) unsigned short Vs[2][64 * 64];
  const int tid = threadIdx.x, lane = tid & 63, w = tid >> 6;
  const int l31 = lane & 31, hi5 = lane >> 5;
  const int bh = blockIdx.y;
  const int q0 = blockIdx.x * 128 + w * 32;
  const unsigned short* Qp = Q + (size_t)bh * TT * DH;
  const unsigned short* Kp = Kx + (size_t)bh * TT * DH;
  const unsigned short* Vp = Vt + (size_t)bh * DH * TT;

  // Q B-frags: lane q = l31, d-slice = j*16 + hi5*8
  bf16x8 qf[4];
#pragma unroll
  for (int j = 0; j < 4; ++j)
    qf[j] = *(const bf16x8*)&Qp[(size_t)(q0 + l31) * DH + j * 16 + hi5 * 8];

  // staging: thread covers rows srow, srow+32; swizzled source granule
  const int srow = tid >> 3;
  const int sg = ((tid & 7) ^ (srow & 7)) * 8;

  float m_run = -1e30f, l_run = 0.f;
  f32x16 oacc[2] = {};

  // prologue: stage tile 0 into buf 0
#pragma unroll
  for (int i = 0; i < 2; ++i) {
    async16(Kp + (size_t)(i * 32 + srow) * DH + sg, &Ks[0][i * 2048 + tid * 8]);
    async16(Vp + (size_t)(i * 32 + srow) * TT + sg, &Vs[0][i * 2048 + tid * 8]);
  }
  __syncthreads();

  int cur = 0;
#pragma unroll 1
  for (int kt = 0; kt < TT / 64; ++kt) {
    // issue next tile's stage into cur^1 (in flight across this iter's compute)
    if (kt + 1 < TT / 64) {
      const int kv1 = (kt + 1) * 64;
#pragma unroll
      for (int i = 0; i < 2; ++i) {
        async16(Kp + (size_t)(kv1 + i * 32 + srow) * DH + sg,
                &Ks[cur ^ 1][i * 2048 + tid * 8]);
        async16(Vp + (size_t)(i * 32 + srow) * TT + kv1 + sg,
                &Vs[cur ^ 1][i * 2048 + tid * 8]);
      }
    }

    // S^T = K . Q^T : sacc[t][reg] = S[k = kt*64 + t*32 + (reg&3)+8*(reg>>2)+4*hi5][q=l31]
    f32x16 sacc[2] = {};
#pragma unroll
    for (int ks16 = 0; ks16 < 4; ++ks16) {
#pragma unroll
      for (int t = 0; t < 2; ++t) {
        bf16x8 kf = *(const bf16x8*)&Ks[cur][(t * 32 + l31) * 64 +
                        (((ks16 * 2 + hi5) ^ (l31 & 7)) * 8)];
        sacc[t] = __builtin_amdgcn_mfma_f32_32x32x16_bf16(kf, qf[ks16], sacc[t], 0, 0, 0);
      }
    }

    // in-register online softmax (q = l31; S already in log2 domain)
    float mt = -1e30f;
#pragma unroll
    for (int t = 0; t < 2; ++t)
#pragma unroll
      for (int r = 0; r < 16; ++r) mt = fmaxf(mt, sacc[t][r]);
    mt = fmaxf(mt, __shfl_xor(mt, 32));
    const float mnew = fmaxf(m_run, mt);
    const float sc = exp2f(m_run - mnew);
    float rs = 0.f;
#pragma unroll
    for (int t = 0; t < 2; ++t)
#pragma unroll
      for (int r = 0; r < 16; ++r) {
        const float pv = exp2f(sacc[t][r] - mnew);
        sacc[t][r] = pv;
        rs += pv;
      }
    rs += __shfl_xor(rs, 32);
    l_run = l_run * sc + rs;
    m_run = mnew;
#pragma unroll
    for (int t = 0; t < 2; ++t)
#pragma unroll
      for (int r = 0; r < 16; ++r) oacc[t][r] *= sc;

    // P -> bf16 pairs in-register. wpk[t*8+j] holds k-pair base(j)+4*hi5,
    // base(j) = (j&1)*2 + (j>>1)*8.
    uint32_t wpk[16];
#pragma unroll
    for (int t = 0; t < 2; ++t)
#pragma unroll
      for (int j = 0; j < 8; ++j)
        wpk[t * 8 + j] = (uint32_t)f2bf(sacc[t][2 * j]) |
                         ((uint32_t)f2bf(sacc[t][2 * j + 1]) << 16);
    // half-exchange: each half sends what the partner needs
    uint32_t xw[8];
#pragma unroll
    for (int t = 0; t < 2; ++t) {
      xw[t * 4 + 0] = __shfl_xor(hi5 ? wpk[t * 8 + 0] : wpk[t * 8 + 2], 32);
      xw[t * 4 + 1] = __shfl_xor(hi5 ? wpk[t * 8 + 1] : wpk[t * 8 + 3], 32);
      xw[t * 4 + 2] = __shfl_xor(hi5 ? wpk[t * 8 + 4] : wpk[t * 8 + 6], 32);
      xw[t * 4 + 3] = __shfl_xor(hi5 ? wpk[t * 8 + 5] : wpk[t * 8 + 7], 32);
    }

    // PV: O^T[d][q] += V^T . P^T, 4 K-slices of 16
#pragma unroll
    for (int ks = 0; ks < 4; ++ks) {
      const int t = ks >> 1, b = (ks & 1) * 4, o = t * 8, xb = t * 4 + (ks & 1) * 2;
      union { uint32_t u[4]; bf16x8 v; } pu;
      pu.u[0] = hi5 ? xw[xb] : wpk[o + b];
      pu.u[1] = hi5 ? xw[xb + 1] : wpk[o + b + 1];
      pu.u[2] = hi5 ? wpk[o + b + 2] : xw[xb];
      pu.u[3] = hi5 ? wpk[o + b + 3] : xw[xb + 1];
#pragma unroll
      for (int dt = 0; dt < 2; ++dt) {
        bf16x8 vf = *(const bf16x8*)&Vs[cur][(dt * 32 + l31) * 64 +
                        (((ks * 2 + hi5) ^ (l31 & 7)) * 8)];
        oacc[dt] = __builtin_amdgcn_mfma_f32_32x32x16_bf16(vf, pu.v, oacc[dt], 0, 0, 0);
      }
    }
    __syncthreads();
    cur ^= 1;
  }

  // epilogue: O^T regs -> LDS bounce (wave-private 4KB in Ks) -> coalesced store
  const float il = 1.0f / l_run;
  unsigned short* bw = &Ks[0][0] + w * 2048;
#pragma unroll
  for (int dt = 0; dt < 2; ++dt)
#pragma unroll
    for (int j = 0; j < 8; ++j) {
      const int dl = (j & 1) * 2 + (j >> 1) * 8 + hi5 * 4;
      const int d = dt * 32 + dl;
      const uint32_t pk = (uint32_t)f2bf(oacc[dt][2 * j] * il) |
                          ((uint32_t)f2bf(oacc[dt][2 * j + 1] * il) << 16);
      const int g = d >> 3, gi = (d >> 1) & 3;
      *(uint32_t*)&bw[l31 * 64 + ((g ^ (l31 & 7)) * 8) + gi * 2] = pk;
    }
  __syncthreads();
  const int bb = bh >> 4, hd = bh & 15;
#pragma unroll
  for (int i = 0; i < 4; ++i) {
    const int row = i * 8 + (lane >> 3);
    const int g = lane & 7;
    bf16x8 vv = *(const bf16x8*)&bw[row * 64 + ((g ^ (row & 7)) * 8)];
    *(bf16x8*)&At[((size_t)bb * TT + q0 + row) * CC + hd * DH + g * 8] = vv;
  }
}

extern "C" void kernel_launch(void* const* d_in, const int* in_sizes, int n_in,
                              void* d_out, int out_size, void* d_ws, size_t ws_size,
                              hipStream_t stream) {
  const float* x = (const float*)d_in[0];
  const float* Wqkv = (const float*)d_in[1];
  const float* bqkv = (const float*)d_in[2];
  const float* Wout = (const float*)d_in[3];
  const float* bout = (const float*)d_in[4];
  float* out = (float*)d_out;

  char* ws = (char*)d_ws;
  unsigned short* Xb  = (unsigned short*)(ws);                      // 16 MB
  unsigned short* WqT = (unsigned short*)(ws + (16ull << 20));      // 6 MB
  unsigned short* WoT = (unsigned short*)(ws + (22ull << 20));      // 2 MB
  unsigned short* Qb  = (unsigned short*)(ws + (24ull << 20));      // 16 MB
  unsigned short* Kb  = (unsigned short*)(ws + (40ull << 20));      // 16 MB
  unsigned short* Vt  = (unsigned short*)(ws + (56ull << 20));      // 16 MB
  unsigned short* At  = (unsigned short*)(ws + (72ull << 20));      // 16 MB (88 total)

  k_cvt<<<dim3((MM * KK) / (256 * 8)), 256, 0, stream>>>(x, Xb);
  k_tcvt<<<dim3(N1 / 32, KK / 32), 256, 0, stream>>>(Wqkv, WqT, KK, N1);
  k_tcvt<<<dim3(CC / 32, KK / 32), 256, 0, stream>>>(Wout, WoT, KK, CC);
  k_gemm<0><<<dim3(N1 / 128, MM / 128), 256, 0, stream>>>(
      Xb, WqT, bqkv, MM, N1, KK, Qb, Kb, Vt, nullptr);
  k_attn<<<dim3(TT / 128, BB * HH), 256, 0, stream>>>(Qb, Kb, Vt, At);
  k_gemm<1><<<dim3(CC / 128, MM / 128), 256, 0, stream>>>(
      At, WoT, bout, MM, CC, KK, nullptr, nullptr, nullptr, out);
}